// Round 15
// baseline (886.158 us; speedup 1.0000x reference)
//
#include <hip/hip_runtime.h>
#include <cstdint>
#include <cstddef>

#define B_   32
#define T_   128
#define H_   1024
#define V_   32000
#define NBT  (B_*T_)   // 4096
#define G3H  (3*H_)    // 3072
#define BH_  (B_*H_)   // 32768
#define NBLK 64
#define NTHR 512
#define JB   16        // columns per block -> 48 W rows = 3 gates x 16

typedef short short8 __attribute__((ext_vector_type(8)));
typedef float f32x4  __attribute__((ext_vector_type(4)));

#define EMB_LDS (V_*4 + NBT*4)   // 144384

__device__ __forceinline__ unsigned short bf16_rtn(float f) {
    unsigned u = __float_as_uint(f);
    u += 0x7FFFu + ((u >> 16) & 1u);
    return (unsigned short)(u >> 16);
}

// ---------- prepass 1: gxT[r][bt] = Wih[r][tok[bt]] + bih[r] ----------
__global__ __launch_bounds__(1024) void gru_embed(
    const float* __restrict__ Wih, const float* __restrict__ bih,
    const int* __restrict__ xs, float* __restrict__ gxT)
{
    extern __shared__ char l[];
    float* rowL = (float*)l;
    int*   tokL = (int*)(l + V_ * 4);
    const int tid = threadIdx.x;
    const int r   = (int)blockIdx.x;

    for (int i = tid; i < NBT; i += 1024) tokL[i] = xs[i];
    const float4* src = (const float4*)(Wih + (size_t)r * V_);
    for (int i = tid; i < V_ / 4; i += 1024) ((float4*)rowL)[i] = src[i];
    __syncthreads();

    const float bias = bih[r];
    float* dst = gxT + (size_t)r * NBT;
    for (int i = tid; i < NBT; i += 1024) dst[i] = rowL[tokL[i]] + bias;
}

// ---------- prepass 2: gx2[bt][r] = gxT[r][bt] ----------
__global__ __launch_bounds__(256) void gru_tr(
    const float* __restrict__ gxT, float* __restrict__ gx2)
{
    __shared__ float tile[32][33];
    const int tx = threadIdx.x & 31;
    const int ty = threadIdx.x >> 5;
    const int c0 = (int)blockIdx.x * 32;
    const int r0 = (int)blockIdx.y * 32;
    #pragma unroll
    for (int ii = 0; ii < 4; ++ii) {
        const int i = ty + ii * 8;
        tile[i][tx] = gxT[(size_t)(r0 + i) * NBT + c0 + tx];
    }
    __syncthreads();
    #pragma unroll
    for (int ii = 0; ii < 4; ++ii) {
        const int i = ty + ii * 8;
        gx2[(size_t)(c0 + i) * G3H + r0 + tx] = tile[tx][i];
    }
}

// ---------- persistent recurrent kernel ----------
// 64 fat blocks (16 cols = 48 W rows each) cut the per-step MALL h-broadcast
// 4x (32MB -> 8MB). Wave (bh, kq4) loads its 16 h-rows x k-quarter ONCE and
// reuses across all 3 gates (W for 3 gates resident in VGPRs). Protocol is
// the r8/r13-verified slack rendezvous: 64 pollers on spread flags + sync,
// publish only after the h-store drain, outp stores after publish.
__global__ __launch_bounds__(NTHR) void gru_persist(
    const float* __restrict__ Whh,   // (3072,1024)
    const float* __restrict__ bhh,   // (3072)
    const float* __restrict__ gx2,   // (4096,3072)
    unsigned*    __restrict__ hpk,   // T x (B,H) packed (bf16hi|bf16lo) h
    int*         __restrict__ flags, // 64*32 ints, zeroed per launch
    float*       __restrict__ outp,  // (B,T,H)
    float*       __restrict__ hidout)// (B,H)
{
    __shared__ float ghp[4][2][48][17];   // [kq4][bh][row][batch16+pad] 26.1 KB

    const int tid  = threadIdx.x;
    const int bid  = (int)blockIdx.x;
    const int j0   = bid * JB;
    const int lane = tid & 63;
    const int wid  = tid >> 6;     // 0..7
    const int bh   = wid & 1;      // batch half
    const int kq4  = wid >> 1;     // k quarter
    const int arow = lane & 15;    // A row (col jj) / B col (batch)
    const int q    = lane >> 4;

    // ---- W A-fragments for ALL 3 gates (split bf16 hi/lo) -> VGPRs once ----
    short8 wAhi[3][8], wAlo[3][8];
    #pragma unroll
    for (int g = 0; g < 3; ++g) {
        const float* wr = Whh + (size_t)(g * H_ + j0 + arow) * H_;
        #pragma unroll
        for (int kkl = 0; kkl < 8; ++kkl) {
            const int ko = (kq4 * 8 + kkl) * 32 + q * 8;
            const float4 w0 = *(const float4*)(wr + ko);
            const float4 w1 = *(const float4*)(wr + ko + 4);
            const float wv[8] = {w0.x,w0.y,w0.z,w0.w,w1.x,w1.y,w1.z,w1.w};
            short8 hi8, lo8;
            #pragma unroll
            for (int j = 0; j < 8; ++j) {
                const unsigned short h = bf16_rtn(wv[j]);
                const float hf = __uint_as_float((unsigned)h << 16);
                hi8[j] = (short)h;
                lo8[j] = (short)bf16_rtn(wv[j] - hf);
            }
            wAhi[g][kkl] = hi8;
            wAlo[g][kkl] = lo8;
        }
    }

    // ---- gate-thread constants: each thread owns one (jj, b) output ----
    const int jj  = tid & 15;      // column within block
    const int b   = tid >> 4;      // batch 0..31
    const int b16 = b & 15;
    const int bh2 = b >> 4;
    const float bb0 = bhh[j0 + jj];
    const float bb1 = bhh[H_ + j0 + jj];
    const float bb2 = bhh[2 * H_ + j0 + jj];
    float hold = 0.f;

    #pragma unroll 1
    for (int t = 0; t < T_; ++t) {
        // gx loads for THIS step (independent of h; issued before the poll)
        const float* gp = gx2 + (size_t)(b * T_ + t) * G3H + j0 + jj;
        const float xg0 = gp[0];
        const float xg1 = gp[H_];
        const float xg2 = gp[2 * H_];

        // ---- slack rendezvous (r8/r13-verified): 64 pollers + sync ----
        if (t > 0 && tid < NBLK) {
            int v;
            do {
                v = __hip_atomic_load(&flags[tid * 32], __ATOMIC_RELAXED,
                                      __HIP_MEMORY_SCOPE_AGENT);
            } while (v < t);
        }
        __syncthreads();

        // ---- B loaded ONCE per wave, reused across 3 gates ----
        f32x4 accA[3], accM[3];
        #pragma unroll
        for (int g = 0; g < 3; ++g) {
            accA[g] = (f32x4){0.f,0.f,0.f,0.f};
            accM[g] = (f32x4){0.f,0.f,0.f,0.f};
        }
        if (t > 0) {
            const unsigned* hb = hpk + (size_t)(t - 1) * BH_
                               + (size_t)(bh * 16 + arow) * H_ + q * 8;
            #pragma unroll
            for (int kkl = 0; kkl < 8; ++kkl) {
                const int ko = (kq4 * 8 + kkl) * 32;
                const uint4 p0 = *(const uint4*)(hb + ko);
                const uint4 p1 = *(const uint4*)(hb + ko + 4);
                short8 bhi, blo;
                bhi[0] = (short)(p0.x >> 16); blo[0] = (short)(p0.x & 0xFFFFu);
                bhi[1] = (short)(p0.y >> 16); blo[1] = (short)(p0.y & 0xFFFFu);
                bhi[2] = (short)(p0.z >> 16); blo[2] = (short)(p0.z & 0xFFFFu);
                bhi[3] = (short)(p0.w >> 16); blo[3] = (short)(p0.w & 0xFFFFu);
                bhi[4] = (short)(p1.x >> 16); blo[4] = (short)(p1.x & 0xFFFFu);
                bhi[5] = (short)(p1.y >> 16); blo[5] = (short)(p1.y & 0xFFFFu);
                bhi[6] = (short)(p1.z >> 16); blo[6] = (short)(p1.z & 0xFFFFu);
                bhi[7] = (short)(p1.w >> 16); blo[7] = (short)(p1.w & 0xFFFFu);
                #pragma unroll
                for (int g = 0; g < 3; ++g) {
                    accA[g] = __builtin_amdgcn_mfma_f32_16x16x32_bf16(wAhi[g][kkl], bhi, accA[g], 0, 0, 0);
                    accM[g] = __builtin_amdgcn_mfma_f32_16x16x32_bf16(wAhi[g][kkl], blo, accM[g], 0, 0, 0);
                    accM[g] = __builtin_amdgcn_mfma_f32_16x16x32_bf16(wAlo[g][kkl], bhi, accM[g], 0, 0, 0);
                }
            }
        }

        // ---- C partials -> LDS (row m=q*4+r per gate, col=arow=batch) ----
        #pragma unroll
        for (int g = 0; g < 3; ++g)
            #pragma unroll
            for (int r = 0; r < 4; ++r)
                ghp[kq4][bh][g * 16 + q * 4 + r][arow] = accA[g][r] + accM[g][r];
        __syncthreads();

        // ---- gates + packed-h publish (all 512 threads, one output each) ----
        float s0 = 0.f, s1 = 0.f, s2 = 0.f;
        #pragma unroll
        for (int k4 = 0; k4 < 4; ++k4) {
            s0 += ghp[k4][bh2][jj][b16];
            s1 += ghp[k4][bh2][16 + jj][b16];
            s2 += ghp[k4][bh2][32 + jj][b16];
        }
        const float rg  = 1.f / (1.f + __expf(-(xg0 + bb0 + s0)));
        const float zg  = 1.f / (1.f + __expf(-(xg1 + bb1 + s1)));
        const float tnn = xg2 + rg * (bb2 + s2);
        const float e   = __expf(-2.f * fabsf(tnn));
        const float m   = (1.f - e) / (1.f + e);
        const float ng  = copysignf(m, tnn);          // tanh, inf-safe
        const float hnew = (1.f - zg) * ng + zg * hold;
        hold = hnew;

        {
            const unsigned short hh = bf16_rtn(hnew);
            const float hf = __uint_as_float((unsigned)hh << 16);
            const unsigned short hl = bf16_rtn(hnew - hf);
            const unsigned pk = ((unsigned)hh << 16) | (unsigned)hl;
            // device-coherent write-through (sc1); relaxed -> no wbl2/inv
            __hip_atomic_store(hpk + (size_t)t * BH_ + (size_t)b * H_ + j0 + jj,
                               pk, __ATOMIC_RELAXED, __HIP_MEMORY_SCOPE_AGENT);
        }

        // ---- drain h stores (vmcnt0 in syncthreads) then publish flag ----
        __syncthreads();
        if (tid == 0) {
            __hip_atomic_store(&flags[bid * 32], t + 1,
                               __ATOMIC_RELAXED, __HIP_MEMORY_SCOPE_AGENT);
        }

        // ---- HBM output stores AFTER publish (off the critical chain) ----
        outp[((size_t)b * T_ + t) * H_ + j0 + jj] = hnew;
        if (t == T_ - 1) hidout[(size_t)b * H_ + j0 + jj] = hnew;
    }
}

extern "C" void kernel_launch(void* const* d_in, const int* in_sizes, int n_in,
                              void* d_out, int out_size, void* d_ws, size_t ws_size,
                              hipStream_t stream) {
    const int*   xs  = (const int*)  d_in[0];
    const float* Wih = (const float*)d_in[1];
    const float* Whh = (const float*)d_in[2];
    const float* bih = (const float*)d_in[3];
    const float* bhh = (const float*)d_in[4];

    float* outp = (float*)d_out;
    float* hid  = outp + (size_t)B_ * T_ * H_;

    char* p = (char*)d_ws;
    unsigned* hpk   = (unsigned*)p;  p += (size_t)T_ * BH_ * 4;    // 16 MB
    float*    gxT   = (float*)p;     p += (size_t)G3H * NBT * 4;   // 50 MB
    float*    gx2   = (float*)p;     p += (size_t)G3H * NBT * 4;   // 50 MB
    int*      flags = (int*)p;                                     // 8 KB

    // zero flags every launch (graph-replay deterministic)
    (void)hipMemsetAsync(flags, 0, (size_t)NBLK * 32 * sizeof(int), stream);

    (void)hipFuncSetAttribute((const void*)gru_embed,
                              hipFuncAttributeMaxDynamicSharedMemorySize,
                              (int)EMB_LDS);

    gru_embed<<<G3H, 1024, EMB_LDS, stream>>>(Wih, bih, xs, gxT);
    gru_tr<<<dim3(NBT / 32, G3H / 32), 256, 0, stream>>>(gxT, gx2);
    gru_persist<<<NBLK, NTHR, 0, stream>>>(
        Whh, bhh, gx2, hpk, flags, outp, hid);

    (void)in_sizes; (void)n_in; (void)out_size; (void)ws_size;
}

// Round 16
// 555.519 us; speedup vs baseline: 1.5952x; 1.5952x over previous
//
#include <hip/hip_runtime.h>
#include <cstdint>
#include <cstddef>

#define B_   32
#define T_   128
#define H_   1024
#define V_   32000
#define NBT  (B_*T_)   // 4096
#define G3H  (3*H_)    // 3072
#define BH_  (B_*H_)   // 32768
#define NBLK 256
#define NTHR 512
#define JB   16        // columns per block -> 48 W rows (3 gates x 16)

typedef short short8 __attribute__((ext_vector_type(8)));
typedef float f32x4  __attribute__((ext_vector_type(4)));

#define EMB_LDS (V_*4 + NBT*4)   // 144384

__device__ __forceinline__ unsigned short bf16_rtn(float f) {
    unsigned u = __float_as_uint(f);
    u += 0x7FFFu + ((u >> 16) & 1u);
    return (unsigned short)(u >> 16);
}

// ---------- prepass 1: gxT[r][bt] = Wih[r][tok[bt]] + bih[r] ----------
__global__ __launch_bounds__(1024) void gru_embed(
    const float* __restrict__ Wih, const float* __restrict__ bih,
    const int* __restrict__ xs, float* __restrict__ gxT)
{
    extern __shared__ char l[];
    float* rowL = (float*)l;
    int*   tokL = (int*)(l + V_ * 4);
    const int tid = threadIdx.x;
    const int r   = (int)blockIdx.x;

    for (int i = tid; i < NBT; i += 1024) tokL[i] = xs[i];
    const float4* src = (const float4*)(Wih + (size_t)r * V_);
    for (int i = tid; i < V_ / 4; i += 1024) ((float4*)rowL)[i] = src[i];
    __syncthreads();

    const float bias = bih[r];
    float* dst = gxT + (size_t)r * NBT;
    for (int i = tid; i < NBT; i += 1024) dst[i] = rowL[tokL[i]] + bias;
}

// ---------- prepass 2: gx2[bt][r] = gxT[r][bt] ----------
__global__ __launch_bounds__(256) void gru_tr(
    const float* __restrict__ gxT, float* __restrict__ gx2)
{
    __shared__ float tile[32][33];
    const int tx = threadIdx.x & 31;
    const int ty = threadIdx.x >> 5;
    const int c0 = (int)blockIdx.x * 32;
    const int r0 = (int)blockIdx.y * 32;
    #pragma unroll
    for (int ii = 0; ii < 4; ++ii) {
        const int i = ty + ii * 8;
        tile[i][tx] = gxT[(size_t)(r0 + i) * NBT + c0 + tx];
    }
    __syncthreads();
    #pragma unroll
    for (int ii = 0; ii < 4; ++ii) {
        const int i = ty + ii * 8;
        gx2[(size_t)(c0 + i) * G3H + r0 + tx] = tile[tx][i];
    }
}

// ---------- persistent recurrent kernel: 2-D partition ----------
// Block (jg = bid&63, bq = bid>>6) owns 16 cols x 3 gates for batches
// bq*8..bq*8+7. 4 independent batch-octet pipelines, each with a 64-block
// r13-style slack rendezvous (poll -> syncthreads -> load). Grid h-broadcast
// = 256 x 32KB = 8 MB/step on 256 active CUs. W (48 rows, split-bf16 hi/lo)
// resident in VGPRs (96 regs). 8 waves = k-eighths; no gate redundancy.
__global__ __launch_bounds__(NTHR) void gru_persist(
    const float* __restrict__ Whh,   // (3072,1024)
    const float* __restrict__ bhh,   // (3072)
    const float* __restrict__ gx2,   // (4096,3072)
    unsigned*    __restrict__ hpk,   // T x (B,H) packed (bf16hi|bf16lo) h
    int*         __restrict__ flags, // 256*32 ints, zeroed per launch
    float*       __restrict__ outp,  // (B,T,H)
    float*       __restrict__ hidout)// (B,H)
{
    __shared__ float ghp[8][48][9];   // [kq8][row][batch8+pad] 13.8 KB

    const int tid  = threadIdx.x;
    const int bid  = (int)blockIdx.x;
    const int jg   = bid & 63;
    const int bq   = bid >> 6;      // batch octet 0..3
    const int j0   = jg * JB;
    const int lane = tid & 63;
    const int kq8  = tid >> 6;      // wave = k-eighth 0..7
    const int arow = lane & 15;     // A row (col jj) / B col
    const int q    = lane >> 4;
    const int bcol = arow & 7;      // batch within octet (dup for arow>=8)

    // ---- W A-fragments for ALL 3 gates (split bf16 hi/lo) -> VGPRs once ----
    short8 wAhi[3][4], wAlo[3][4];
    #pragma unroll
    for (int g = 0; g < 3; ++g) {
        const float* wr = Whh + (size_t)(g * H_ + j0 + arow) * H_;
        #pragma unroll
        for (int kkl = 0; kkl < 4; ++kkl) {
            const int ko = (kq8 * 4 + kkl) * 32 + q * 8;
            const float4 w0 = *(const float4*)(wr + ko);
            const float4 w1 = *(const float4*)(wr + ko + 4);
            const float wv[8] = {w0.x,w0.y,w0.z,w0.w,w1.x,w1.y,w1.z,w1.w};
            short8 hi8, lo8;
            #pragma unroll
            for (int j = 0; j < 8; ++j) {
                const unsigned short h = bf16_rtn(wv[j]);
                const float hf = __uint_as_float((unsigned)h << 16);
                hi8[j] = (short)h;
                lo8[j] = (short)bf16_rtn(wv[j] - hf);
            }
            wAhi[g][kkl] = hi8;
            wAlo[g][kkl] = lo8;
        }
    }

    // ---- gate-thread constants (tid<128): jj = tid&15, c = tid>>4 (0..7) ----
    const int jj = tid & 15;
    const int c  = tid >> 4;          // valid when tid<128
    const int b  = bq * 8 + (c & 7);  // this thread's batch
    const float bb0 = bhh[j0 + jj];
    const float bb1 = bhh[H_ + j0 + jj];
    const float bb2 = bhh[2 * H_ + j0 + jj];
    float hold = 0.f;

    #pragma unroll 1
    for (int t = 0; t < T_; ++t) {
        // gx loads for THIS step (independent of h; issued before the poll)
        float xg0 = 0.f, xg1 = 0.f, xg2 = 0.f;
        if (tid < 128) {
            const float* gp = gx2 + (size_t)(b * T_ + t) * G3H + j0 + jj;
            xg0 = gp[0];
            xg1 = gp[H_];
            xg2 = gp[2 * H_];
        }

        // ---- group rendezvous (r13 shape): 64 pollers on this octet's
        //      producers, then the slack barrier before any h consumption ----
        if (t > 0 && tid < 64) {
            const int* fp = flags + (bq * 64 + tid) * 32;
            int v;
            do {
                v = __hip_atomic_load(fp, __ATOMIC_RELAXED,
                                      __HIP_MEMORY_SCOPE_AGENT);
            } while (v < t);
        }
        __syncthreads();

        // ---- B loads (32KB/block, this octet only) + chained MFMAs ----
        f32x4 accA[3], accM[3];
        #pragma unroll
        for (int g = 0; g < 3; ++g) {
            accA[g] = (f32x4){0.f,0.f,0.f,0.f};
            accM[g] = (f32x4){0.f,0.f,0.f,0.f};
        }
        if (t > 0) {
            const unsigned* hb = hpk + (size_t)(t - 1) * BH_
                               + (size_t)(bq * 8 + bcol) * H_ + q * 8;
            #pragma unroll
            for (int kkl = 0; kkl < 4; ++kkl) {
                const int ko = (kq8 * 4 + kkl) * 32;
                const uint4 p0 = *(const uint4*)(hb + ko);
                const uint4 p1 = *(const uint4*)(hb + ko + 4);
                short8 bhi, blo;
                bhi[0] = (short)(p0.x >> 16); blo[0] = (short)(p0.x & 0xFFFFu);
                bhi[1] = (short)(p0.y >> 16); blo[1] = (short)(p0.y & 0xFFFFu);
                bhi[2] = (short)(p0.z >> 16); blo[2] = (short)(p0.z & 0xFFFFu);
                bhi[3] = (short)(p0.w >> 16); blo[3] = (short)(p0.w & 0xFFFFu);
                bhi[4] = (short)(p1.x >> 16); blo[4] = (short)(p1.x & 0xFFFFu);
                bhi[5] = (short)(p1.y >> 16); blo[5] = (short)(p1.y & 0xFFFFu);
                bhi[6] = (short)(p1.z >> 16); blo[6] = (short)(p1.z & 0xFFFFu);
                bhi[7] = (short)(p1.w >> 16); blo[7] = (short)(p1.w & 0xFFFFu);
                #pragma unroll
                for (int g = 0; g < 3; ++g) {
                    accA[g] = __builtin_amdgcn_mfma_f32_16x16x32_bf16(wAhi[g][kkl], bhi, accA[g], 0, 0, 0);
                    accM[g] = __builtin_amdgcn_mfma_f32_16x16x32_bf16(wAhi[g][kkl], blo, accM[g], 0, 0, 0);
                    accM[g] = __builtin_amdgcn_mfma_f32_16x16x32_bf16(wAlo[g][kkl], bhi, accM[g], 0, 0, 0);
                }
            }
        }

        // ---- C partials -> LDS (row m=q*4+r per gate, col=batch; lanes with
        //      duplicate batch (arow>=8) masked off) ----
        if (arow < 8) {
            #pragma unroll
            for (int g = 0; g < 3; ++g)
                #pragma unroll
                for (int r = 0; r < 4; ++r)
                    ghp[kq8][g * 16 + q * 4 + r][arow] = accA[g][r] + accM[g][r];
        }
        __syncthreads();

        // ---- gates + packed-h publish (threads 0..127) ----
        float hnew = 0.f;
        if (tid < 128) {
            float s0 = 0.f, s1 = 0.f, s2 = 0.f;
            #pragma unroll
            for (int k8 = 0; k8 < 8; ++k8) {
                s0 += ghp[k8][jj][c];
                s1 += ghp[k8][16 + jj][c];
                s2 += ghp[k8][32 + jj][c];
            }
            const float rg  = 1.f / (1.f + __expf(-(xg0 + bb0 + s0)));
            const float zg  = 1.f / (1.f + __expf(-(xg1 + bb1 + s1)));
            const float tnn = xg2 + rg * (bb2 + s2);
            const float e   = __expf(-2.f * fabsf(tnn));
            const float m   = (1.f - e) / (1.f + e);
            const float ng  = copysignf(m, tnn);          // tanh, inf-safe
            hnew = (1.f - zg) * ng + zg * hold;
            hold = hnew;

            const unsigned short hh = bf16_rtn(hnew);
            const float hf = __uint_as_float((unsigned)hh << 16);
            const unsigned short hl = bf16_rtn(hnew - hf);
            const unsigned pk = ((unsigned)hh << 16) | (unsigned)hl;
            // device-coherent write-through (sc1); relaxed -> no wbl2/inv
            __hip_atomic_store(hpk + (size_t)t * BH_ + (size_t)b * H_ + j0 + jj,
                               pk, __ATOMIC_RELAXED, __HIP_MEMORY_SCOPE_AGENT);
        }

        // ---- drain h stores (vmcnt0 in syncthreads) then publish flag ----
        __syncthreads();
        if (tid == 0) {
            __hip_atomic_store(&flags[bid * 32], t + 1,
                               __ATOMIC_RELAXED, __HIP_MEMORY_SCOPE_AGENT);
        }

        // ---- HBM output stores AFTER publish (off the critical chain) ----
        if (tid < 128) {
            outp[((size_t)b * T_ + t) * H_ + j0 + jj] = hnew;
            if (t == T_ - 1) hidout[(size_t)b * H_ + j0 + jj] = hnew;
        }
    }
}

extern "C" void kernel_launch(void* const* d_in, const int* in_sizes, int n_in,
                              void* d_out, int out_size, void* d_ws, size_t ws_size,
                              hipStream_t stream) {
    const int*   xs  = (const int*)  d_in[0];
    const float* Wih = (const float*)d_in[1];
    const float* Whh = (const float*)d_in[2];
    const float* bih = (const float*)d_in[3];
    const float* bhh = (const float*)d_in[4];

    float* outp = (float*)d_out;
    float* hid  = outp + (size_t)B_ * T_ * H_;

    char* p = (char*)d_ws;
    unsigned* hpk   = (unsigned*)p;  p += (size_t)T_ * BH_ * 4;    // 16 MB
    float*    gxT   = (float*)p;     p += (size_t)G3H * NBT * 4;   // 50 MB
    float*    gx2   = (float*)p;     p += (size_t)G3H * NBT * 4;   // 50 MB
    int*      flags = (int*)p;                                     // 32 KB

    // zero flags every launch (graph-replay deterministic)
    (void)hipMemsetAsync(flags, 0, (size_t)NBLK * 32 * sizeof(int), stream);

    (void)hipFuncSetAttribute((const void*)gru_embed,
                              hipFuncAttributeMaxDynamicSharedMemorySize,
                              (int)EMB_LDS);

    gru_embed<<<G3H, 1024, EMB_LDS, stream>>>(Wih, bih, xs, gxT);
    gru_tr<<<dim3(NBT / 32, G3H / 32), 256, 0, stream>>>(gxT, gx2);
    gru_persist<<<NBLK, NTHR, 0, stream>>>(
        Whh, bhh, gx2, hpk, flags, outp, hid);

    (void)in_sizes; (void)n_in; (void)out_size; (void)ws_size;
}